// Round 3
// baseline (23.948 us; speedup 1.0000x reference)
//
#include <hip/hip_runtime.h>

// out[i,j,k] = sum_h X[i+1,h]*X[j+1,h]*Wp[h,k] + b[k]
// (the (pred+pred^T)/2 symmetrization cancels the antisymmetric d-terms;
//  prod_term is symmetric => compute upper-triangular tiles, mirror-store)
//
// R2: fold W into the j-operand at staging (syw = X_j * w_k), vectorize all
// LDS reads to ds_read_b128, triangular grid (300 blocks, no early-exit).

constexpr int Hd   = 768;    // hidden
constexpr int OUT  = 382;    // output rows/cols (L-2)
constexpr int TILE = 16;     // output tile (i and j)
constexpr int NT   = 24;     // ceil(382/16)
constexpr int NBLK = NT * (NT + 1) / 2;  // 300 upper-tri tiles
constexpr int HC   = 256;    // h chunk staged in LDS
constexpr int SXS  = HC + 4; // sx row stride (260 ≡ 4 mod 32: conflict-free)
constexpr int SYS  = 2 * HC + 4; // syw row stride (516 ≡ 4 mod 32: 2-way max)
constexpr int KOFF = HC;     // k=1 offset within syw row (16B-aligned)

__global__ __launch_bounds__(256)
void pairhead_kernel(const float* __restrict__ X,
                     const float* __restrict__ W,
                     const float* __restrict__ bias,
                     float* __restrict__ out) {
  // triangular block index -> (bi, bj), bj >= bi
  const int m = blockIdx.x;
  int bi = (int)(((2 * NT + 1) - sqrtf((float)((2 * NT + 1) * (2 * NT + 1) - 8 * m))) * 0.5f);
  // cum(r) = tiles before row r = r*NT - r*(r-1)/2 ; fix fp rounding
  while (bi > 0 && (bi * NT - bi * (bi - 1) / 2) > m) --bi;
  while (((bi + 1) * NT - (bi + 1) * bi / 2) <= m) ++bi;
  const int bj = bi + (m - (bi * NT - bi * (bi - 1) / 2));

  __shared__ float sx[TILE * SXS];        // X rows of the i-tile
  __shared__ float syw[TILE * SYS];       // X_j * w0 at [c], X_j * w1 at [KOFF+c]

  const int t  = threadIdx.x;             // 0..255
  const int ti = t >> 4;
  const int tj = t & 15;
  const int i  = bi * TILE + ti;
  const int j  = bj * TILE + tj;

  float a0 = 0.f, a1 = 0.f;

  for (int h0 = 0; h0 < Hd; h0 += HC) {
    __syncthreads();
    // stage: 16 rows x (HC/4)=64 float4 per operand; 4 per thread each
    #pragma unroll
    for (int u = t; u < TILE * HC / 4; u += 256) {
      const int r  = u >> 6;
      const int c  = (u & 63) << 2;
      // i-side
      const int gi = bi * TILE + r;
      float4 v = make_float4(0.f, 0.f, 0.f, 0.f);
      if (gi < OUT) v = *reinterpret_cast<const float4*>(X + (size_t)(gi + 1) * Hd + h0 + c);
      *reinterpret_cast<float4*>(&sx[r * SXS + c]) = v;
      // j-side, folded with W: wa = {w[c,0],w[c,1],w[c+1,0],w[c+1,1]}, wb next
      const int gj = bj * TILE + r;
      float4 xv = make_float4(0.f, 0.f, 0.f, 0.f);
      if (gj < OUT) xv = *reinterpret_cast<const float4*>(X + (size_t)(gj + 1) * Hd + h0 + c);
      const float4 wa = *reinterpret_cast<const float4*>(W + (size_t)(h0 + c) * 2);
      const float4 wb = *reinterpret_cast<const float4*>(W + (size_t)(h0 + c) * 2 + 4);
      float4 y0 = make_float4(xv.x * wa.x, xv.y * wa.z, xv.z * wb.x, xv.w * wb.z);
      float4 y1 = make_float4(xv.x * wa.y, xv.y * wa.w, xv.z * wb.y, xv.w * wb.w);
      *reinterpret_cast<float4*>(&syw[r * SYS + c]) = y0;
      *reinterpret_cast<float4*>(&syw[r * SYS + KOFF + c]) = y1;
    }
    __syncthreads();

    const float* xrow = &sx[ti * SXS];
    const float* yrow = &syw[tj * SYS];
    #pragma unroll 16
    for (int c = 0; c < HC; c += 4) {
      const float4 xi = *reinterpret_cast<const float4*>(xrow + c);
      const float4 y0 = *reinterpret_cast<const float4*>(yrow + c);
      const float4 y1 = *reinterpret_cast<const float4*>(yrow + KOFF + c);
      a0 += xi.x * y0.x; a1 += xi.x * y1.x;
      a0 += xi.y * y0.y; a1 += xi.y * y1.y;
      a0 += xi.z * y0.z; a1 += xi.z * y1.z;
      a0 += xi.w * y0.w; a1 += xi.w * y1.w;
    }
  }

  if (i < OUT && j < OUT) {
    const float v0 = a0 + bias[0];
    const float v1 = a1 + bias[1];
    *reinterpret_cast<float2*>(&out[((size_t)i * OUT + j) * 2]) = make_float2(v0, v1);
    if (bi != bj) {  // mirror tile (diagonal tiles already cover both orders)
      *reinterpret_cast<float2*>(&out[((size_t)j * OUT + i) * 2]) = make_float2(v0, v1);
    }
  }
}

extern "C" void kernel_launch(void* const* d_in, const int* in_sizes, int n_in,
                              void* d_out, int out_size, void* d_ws, size_t ws_size,
                              hipStream_t stream) {
  const float* X    = (const float*)d_in[0];  // (1,384,768) fp32
  // d_in[1] = sequence_lengths (dead: output is independent of it)
  const float* W    = (const float*)d_in[2];  // (1536,2) fp32; rows [0,768) = Wp
  const float* bias = (const float*)d_in[3];  // (2,)
  float* out = (float*)d_out;                 // (1,382,382,2) fp32

  pairhead_kernel<<<dim3(NBLK, 1, 1), dim3(256, 1, 1), 0, stream>>>(X, W, bias, out);
}